// Round 7
// baseline (565.644 us; speedup 1.0000x reference)
//
#include <hip/hip_runtime.h>
#include <math.h>

#define N_ENTC 30000
#define ALL_RELC 221
#define NDIM 32
#define EVAL_RELC 86
#define BB 16
#define NE 120000
#define ROW 512            /* BB*NDIM floats per qacc row */
#define NSCAN 120          /* scan stripes; NSCAN*EPB == NE */
#define EPB 1000
#define MW 938             /* bitmask words for 30000 entities */
#define MAXL 256           /* compacted-list capacity per (layer,direction) */
#define GT 1024            /* gather block threads (16 waves) */

// Three regular dispatches, no device fences, no done counters.
//  K1 k_scan   : 120 blocks [r5-proven]. Records + counts; block1 zeroes qacc.
//  K2 k_gather : ONE block x 1024 threads. Startup paid once: counts, rel0
//                (28 KB) -> LDS, relw recomputed [r5-proven], ~500 records
//                compacted to LDS lists [r4-proven]. 16 waves independently
//                process L2 records: LDS match loop -> pre[32] in REGISTERS
//                (ALL loops touching pre[] are #pragma unroll'd -- r6's 479us
//                regression was pre[] spilling to scratch via the un-unrolled
//                lin1 k-loop; rule #20) -> lin1 -> msg2 atomics. No barriers
//                in the record loop.
//  K3 k_fin    : 1 block [r0-proven verbatim]. Stream boundary = sync.

__global__ __launch_bounds__(512) void k_scan(
    const int* __restrict__ head, const int* __restrict__ tail,
    const int* __restrict__ eh, const int* __restrict__ et,
    const int* __restrict__ er, const float* __restrict__ ew,
    int4* __restrict__ recs, int* __restrict__ counts,
    float* __restrict__ qaccB)
{
    __shared__ unsigned mH[MW], mT[MW];
    __shared__ int s_src[32];
    __shared__ int s_cnt[4];
    const int t = threadIdx.x, bid = blockIdx.x;

    if (t < 32) s_src[t] = (t < BB) ? head[t] : tail[t - BB];
    for (int i = t; i < MW; i += 512) { mH[i] = 0u; mT[i] = 0u; }
    if (t < 4) s_cnt[t] = 0;
    __syncthreads();
    if (t < BB) {
        int h = s_src[t], q = s_src[BB + t];
        atomicOr(&mH[h >> 5], 1u << (h & 31));
        atomicOr(&mT[q >> 5], 1u << (q & 31));
    }
    __syncthreads();

    const int e0 = bid * EPB;
    const int4* eh4 = (const int4*)(eh + e0);
    const int4* et4 = (const int4*)(et + e0);
    for (int p = t; p < EPB / 4; p += 512) {
        int4 h4 = eh4[p], t4 = et4[p];
        int hv[4] = {h4.x, h4.y, h4.z, h4.w};
        int tv[4] = {t4.x, t4.y, t4.z, t4.w};
#pragma unroll
        for (int c = 0; c < 4; c++) {
            int e = e0 + 4 * p + c, h = hv[c], tt = tv[c];
            bool hH = (mH[h >> 5] >> (h & 31)) & 1u;
            bool hT = (mT[h >> 5] >> (h & 31)) & 1u;
            bool tT = (mT[tt >> 5] >> (tt & 31)) & 1u;
            bool tH = (mH[tt >> 5] >> (tt & 31)) & 1u;
            if (!(hH | hT | tT | tH)) continue;
            int r = er[e];
            int wb = __float_as_int(ew[e]);
            if (hH) { // d=0 layer-1: srcmask over head ids
                unsigned m = 0;
#pragma unroll
                for (int b = 0; b < BB; b++) m |= (s_src[b] == h) ? (1u << b) : 0u;
                int pos = atomicAdd(&s_cnt[0], 1);
                recs[(size_t)bid * EPB + pos] = make_int4(tt, r | (int)(m << 8), wb, h);
            }
            if (hT) { // d=1 layer-1: srcmask over tail ids
                unsigned m = 0;
#pragma unroll
                for (int b = 0; b < BB; b++) m |= (s_src[BB + b] == h) ? (1u << b) : 0u;
                int pos = atomicAdd(&s_cnt[1], 1);
                recs[(size_t)NE + bid * EPB + pos] = make_int4(tt, r | (int)(m << 8), wb, h);
            }
            if (tT) { // d=0 layer-2: canon = first matching tail slot
                unsigned m = 0;
#pragma unroll
                for (int b = 0; b < BB; b++) m |= (s_src[BB + b] == tt) ? (1u << b) : 0u;
                int canon = __ffs(m) - 1;
                int pos = atomicAdd(&s_cnt[2], 1);
                recs[(size_t)2 * NE + bid * EPB + pos] = make_int4(h, r | (canon << 8), wb, tt);
            }
            if (tH) { // d=1 layer-2: canon = first matching head slot
                unsigned m = 0;
#pragma unroll
                for (int b = 0; b < BB; b++) m |= (s_src[b] == tt) ? (1u << b) : 0u;
                int canon = __ffs(m) - 1;
                int pos = atomicAdd(&s_cnt[3], 1);
                recs[(size_t)3 * NE + bid * EPB + pos] = make_int4(h, r | (canon << 8), wb, tt);
            }
        }
    }
    __syncthreads();
    if (t < 4) counts[bid * 4 + t] = s_cnt[t];

    if (bid == 1) { // zero qacc (both directions)
        for (int i = t; i < 2 * BB * ROW; i += 512) qaccB[i] = 0.f;
    }
}

__global__ __launch_bounds__(GT) void k_gather(
    const int* __restrict__ head, const int* __restrict__ tail,
    const float* __restrict__ ent_emb, const float* __restrict__ rel_embs,
    const float* __restrict__ Wlin, const float* __restrict__ blin,
    const float* __restrict__ Wrel, const float* __restrict__ brel,
    const float* __restrict__ Watt, const float* __restrict__ batt,
    const int4* __restrict__ recs, const int* __restrict__ counts,
    float* __restrict__ qaccB)
{
    __shared__ int s_src[32];
    __shared__ int s_cnt[NSCAN * 4];
    __shared__ float s_ht[BB * 64];              // [b][head(32)|tail(32)]
    __shared__ float s_h5[2 * BB * 5];           // [l][b][j]
    __shared__ float s_relw[2 * BB * ALL_RELC];  // [l][b][r] (recomputed)
    __shared__ float s_rel0[ALL_RELC * NDIM];    // layer-0 rel embeddings
    __shared__ int4 s_l1[2][MAXL];
    __shared__ int4 s_l2[2][MAXL];
    __shared__ int s_lc[4];                      // l1c0,l1c1,l2c0,l2c1
    __shared__ float sW[NDIM * NDIM];
    __shared__ float sb[NDIM];
    const int t = threadIdx.x;

    // ---- phase 0: parallel preloads ----
    if (t < 32) s_src[t] = (t < BB) ? head[t] : tail[t - BB];
    if (t < NSCAN) ((int4*)s_cnt)[t] = ((const int4*)counts)[t];
    for (int i = t; i < ALL_RELC * NDIM; i += GT) s_rel0[i] = rel_embs[i];
    for (int i = t; i < NDIM * NDIM; i += GT) sW[i] = Wlin[i]; // layer 0
    if (t < NDIM) sb[t] = blin[t];
    if (t < 4) s_lc[t] = 0;
    __syncthreads();

    // ---- phase 1: src-emb + compact all records into LDS lists ----
    for (int i = t; i < BB * NDIM; i += GT) {
        int b = i >> 5, k = i & 31;
        s_ht[b * 64 + k] = ent_emb[(size_t)s_src[b] * NDIM + k];
        s_ht[b * 64 + 32 + k] = ent_emb[(size_t)s_src[BB + b] * NDIM + k];
    }
    {
        // 8 threads per stripe -> all stripes' loads issued concurrently
        const int ss = t >> 3, slot = t & 7;
        if (ss < NSCAN) {
#pragma unroll
            for (int li = 0; li < 4; li++) {
                int c = s_cnt[ss * 4 + li];
                int dd = li & 1;
                for (int q = slot; q < c; q += 8) {
                    int4 lr = recs[(size_t)li * NE + (size_t)ss * EPB + q];
                    int pos = atomicAdd(&s_lc[li], 1);
                    if (li < 2) { if (pos < MAXL) s_l1[dd][pos] = lr; }
                    else        { if (pos < MAXL) s_l2[dd][pos] = lr; }
                }
            }
        }
    }
    __syncthreads();

    // ---- phase 2: recompute relation-attention weights (r5-proven) ----
    if (t < 2 * BB * 5) { // h5[l][b][j] = relu(ht @ Wrel[l] + brel[l])
        int l = t / (BB * 5), rem = t % (BB * 5), b = rem / 5, j = rem % 5;
        float s = brel[l * 5 + j];
        for (int k = 0; k < 64; k++)
            s += s_ht[b * 64 + k] * Wrel[l * 320 + k * 5 + j];
        s_h5[t] = fmaxf(s, 0.f);
    }
    __syncthreads();
    for (int i = t; i < 2 * BB * ALL_RELC; i += GT) {
        int l = i / (BB * ALL_RELC), rem = i % (BB * ALL_RELC);
        int b = rem / ALL_RELC, r = rem % ALL_RELC;
        float s = batt[l * ALL_RELC + r];
        for (int j = 0; j < 5; j++)
            s += s_h5[l * BB * 5 + b * 5 + j] * Watt[l * 5 * ALL_RELC + j * ALL_RELC + r];
        s_relw[i] = 1.0f / (1.0f + expf(-s));
    }
    __syncthreads();

    // ---- phase 3: waves independently process L2 records (flat list) ----
    const int c10 = min(s_lc[0], MAXL), c11 = min(s_lc[1], MAXL);
    const int tot0 = min(s_lc[2], MAXL), tot1 = min(s_lc[3], MAXL);
    const int tot = tot0 + tot1;
    const int wid = t >> 6, lane = t & 63;
    const int bq = lane >> 2, js = (lane & 3) * 8;
    const float* rel1g = rel_embs + (size_t)ALL_RELC * NDIM;
    for (int g = wid; g < tot; g += GT / 64) {
        const int d = (g >= tot0) ? 1 : 0;
        int4 rec = s_l2[d][d ? g - tot0 : g];
        const int hrow = rec.x, r = rec.y & 255, canon = (rec.y >> 8) & 15;
        const float w2 = __int_as_float(rec.z);
        // hoisted (latency hidden under match loop)
        float r1[8];
#pragma unroll
        for (int jj = 0; jj < 8; jj++) r1[jj] = rel1g[r * NDIM + js + jj];
        const float cf2 = s_relw[BB * ALL_RELC + bq * ALL_RELC + r] * w2;
        // pre[bq][*]: gather matched layer-1 messages (r5 accumulation order).
        // EVERY loop indexing pre[] is fully unrolled -> pre stays in VGPRs
        // (r6 regression: un-unrolled lin1 k-loop put pre[] in scratch).
        float pre[NDIM];
#pragma unroll
        for (int k = 0; k < NDIM; k++) pre[k] = 0.f;
        const int c1 = d ? c11 : c10;
        for (int m = 0; m < c1; m++) {
            int4 lr = s_l1[d][m];
            if (lr.x != hrow) continue;
            unsigned msk = ((unsigned)lr.y) >> 8;
            if (!((msk >> bq) & 1u)) continue;
            int rr = lr.y & 255;
            float cf = s_relw[bq * ALL_RELC + rr] * __int_as_float(lr.z);
#pragma unroll
            for (int k = 0; k < NDIM; k++)
                pre[k] += cf * s_ht[bq * 64 + d * 32 + k] * s_rel0[rr * NDIM + k];
        }
        // lin1 (exact r0 serial k-order) + msg2 atomic, j-slice per lane
#pragma unroll
        for (int jj = 0; jj < 8; jj++) {
            int j = js + jj;
            float a = sb[j];
#pragma unroll
            for (int k = 0; k < NDIM; k++)
                a += pre[k] * sW[k * NDIM + j];
            float v = fmaxf(a, 0.f) * cf2 * r1[jj];
            atomicAdd(qaccB + (size_t)d * BB * ROW + canon * ROW + bq * NDIM + j, v);
        }
    }
}

__global__ __launch_bounds__(512) void k_fin(
    const int* __restrict__ head, const int* __restrict__ tail,
    const float* __restrict__ ent_emb, const float* __restrict__ Wlin,
    const float* __restrict__ blin, const float* __restrict__ Wr,
    const float* __restrict__ br, const float* __restrict__ qaccB,
    float* __restrict__ out)
{
    __shared__ float sx[BB * 128]; // hemb|temb|head_hid|tail_hid
    __shared__ float sW[NDIM * NDIM];
    __shared__ float sb[NDIM];
    __shared__ int s_src[32];
    __shared__ int s_canon[2][BB];
    const int t = threadIdx.x;

    if (t < 32) s_src[t] = (t < BB) ? head[t] : tail[t - BB];
    for (int i = t; i < NDIM * NDIM; i += 512) sW[i] = Wlin[NDIM * NDIM + i]; // layer 1
    if (t < NDIM) sb[t] = blin[NDIM + t];
    __syncthreads();
    if (t < 2 * BB) {
        int d = t >> 4, b = t & 15;
        int q = s_src[(1 - d) * BB + b];
        int c = 0;
        for (int bb = 0; bb < BB; bb++)
            if (s_src[(1 - d) * BB + bb] == q) { c = bb; break; }
        s_canon[d][b] = c;
    }
    {
        int b = t >> 5, k = t & 31;
        sx[b * 128 + k] = ent_emb[(size_t)s_src[b] * NDIM + k];           // hemb
        sx[b * 128 + 32 + k] = ent_emb[(size_t)s_src[BB + b] * NDIM + k]; // temb
    }
    __syncthreads();
    for (int d = 0; d < 2; d++) { // layer-2 linear on (canon,b) segments
        int b = t >> 5, j = t & 31;
        const float* hrow = qaccB + (size_t)d * BB * ROW + s_canon[d][b] * ROW + b * NDIM;
        float s = sb[j];
        for (int k = 0; k < NDIM; k++)
            s += hrow[k] * sW[k * NDIM + j];
        // d=0 (init=head, query=tail) -> tail_hid (col 96); d=1 -> head_hid (col 64)
        sx[b * 128 + (d == 0 ? 96 : 64) + j] = fmaxf(s, 0.f);
    }
    __syncthreads();
    for (int o = t; o < BB * EVAL_RELC; o += 512) {
        int b = o / EVAL_RELC, r = o % EVAL_RELC;
        float s = br[r];
        for (int k = 0; k < 128; k++)
            s += sx[b * 128 + k] * Wr[k * EVAL_RELC + r];
        out[o] = s;
    }
}

extern "C" void kernel_launch(void* const* d_in, const int* in_sizes, int n_in,
                              void* d_out, int out_size, void* d_ws,
                              size_t ws_size, hipStream_t stream)
{
    const int* head = (const int*)d_in[0];
    const int* tail = (const int*)d_in[1];
    const int* eh = (const int*)d_in[2];
    const int* et = (const int*)d_in[3];
    const int* er = (const int*)d_in[4];
    const float* ew = (const float*)d_in[5];
    const float* ent_emb = (const float*)d_in[6];
    const float* rel_embs = (const float*)d_in[7];
    const float* Wlin = (const float*)d_in[8];
    const float* blin = (const float*)d_in[9];
    const float* Wrel = (const float*)d_in[10];
    const float* brel = (const float*)d_in[11];
    const float* Watt = (const float*)d_in[12];
    const float* batt = (const float*)d_in[13];
    const float* Wr = (const float*)d_in[14];
    const float* br = (const float*)d_in[15];
    float* out = (float*)d_out;
    float* ws = (float*)d_ws;

    // ---- workspace carve (~7.8 MB) ----
    int4* recs = (int4*)ws;                           // [4][NE] int4
    int* counts = (int*)(recs + (size_t)4 * NE);      // [NSCAN][4]
    float* qaccB = (float*)(counts + 4 * NSCAN);      // [2][16][512]

    k_scan<<<NSCAN, 512, 0, stream>>>(head, tail, eh, et, er, ew,
                                      recs, counts, qaccB);
    k_gather<<<1, GT, 0, stream>>>(head, tail, ent_emb, rel_embs,
                                   Wlin, blin, Wrel, brel, Watt, batt,
                                   recs, counts, qaccB);
    k_fin<<<1, 512, 0, stream>>>(head, tail, ent_emb, Wlin, blin, Wr, br,
                                 qaccB, out);
}

// Round 8
// 131.342 us; speedup vs baseline: 4.3067x; 4.3067x over previous
//
#include <hip/hip_runtime.h>
#include <math.h>

#define N_ENTC 30000
#define ALL_RELC 221
#define NDIM 32
#define EVAL_RELC 86
#define BB 16
#define NE 120000
#define ROW 512            /* BB*NDIM floats per entity row */
#define NSCAN 120          /* scan stripes; NSCAN*EPB == NE */
#define EPB 1000
#define MW 938             /* bitmask words for 30000 entities */

// Three regular dispatches, all 120-block wide (r0's proven grid shape).
//  K1 k_scan      : r0-verbatim. Records, counts, hidB row zeroing for L2
//                   heads, block0: relw -> global, block1: zero qacc + done=0.
//  K2 k_msg1      : r0-verbatim. Layer-1 messages scattered into hidB.
//  K3 k_linmsg2fin: 120x512. r1-phaseC-verbatim fused lin1+msg2 (hidC
//                   eliminated), then syncthreads+threadfence+done counter;
//                   LAST block runs r0-verbatim fin. (Done-counter fin
//                   pattern proven in r3/r4/r5.)

__global__ __launch_bounds__(512) void k_scan(
    const int* __restrict__ head, const int* __restrict__ tail,
    const int* __restrict__ eh, const int* __restrict__ et,
    const int* __restrict__ er, const float* __restrict__ ew,
    const float* __restrict__ ent_emb,
    const float* __restrict__ Wrel, const float* __restrict__ brel,
    const float* __restrict__ Watt, const float* __restrict__ batt,
    int4* __restrict__ recs, int* __restrict__ counts,
    float* __restrict__ relwG, float* __restrict__ hidB,
    float* __restrict__ qaccB, int* __restrict__ done)
{
    __shared__ unsigned mH[MW], mT[MW];
    __shared__ int s_src[32];
    __shared__ int s_cnt[4];
    __shared__ float s_ht[BB * 64];
    __shared__ float s_h5[BB * 5];
    const int t = threadIdx.x, bid = blockIdx.x;

    if (t < 32) s_src[t] = (t < BB) ? head[t] : tail[t - BB];
    for (int i = t; i < MW; i += 512) { mH[i] = 0u; mT[i] = 0u; }
    if (t < 4) s_cnt[t] = 0;
    __syncthreads();
    if (t < BB) {
        int h = s_src[t], q = s_src[BB + t];
        atomicOr(&mH[h >> 5], 1u << (h & 31));
        atomicOr(&mT[q >> 5], 1u << (q & 31));
    }
    __syncthreads();

    const int e0 = bid * EPB;
    const int4* eh4 = (const int4*)(eh + e0);
    const int4* et4 = (const int4*)(et + e0);
    for (int p = t; p < EPB / 4; p += 512) {
        int4 h4 = eh4[p], t4 = et4[p];
        int hv[4] = {h4.x, h4.y, h4.z, h4.w};
        int tv[4] = {t4.x, t4.y, t4.z, t4.w};
#pragma unroll
        for (int c = 0; c < 4; c++) {
            int e = e0 + 4 * p + c, h = hv[c], tt = tv[c];
            bool hH = (mH[h >> 5] >> (h & 31)) & 1u;
            bool hT = (mT[h >> 5] >> (h & 31)) & 1u;
            bool tT = (mT[tt >> 5] >> (tt & 31)) & 1u;
            bool tH = (mH[tt >> 5] >> (tt & 31)) & 1u;
            if (!(hH | hT | tT | tH)) continue;
            int r = er[e];
            int wb = __float_as_int(ew[e]);
            if (hH) { // d=0 layer-1: srcmask over head ids
                unsigned m = 0;
#pragma unroll
                for (int b = 0; b < BB; b++) m |= (s_src[b] == h) ? (1u << b) : 0u;
                int pos = atomicAdd(&s_cnt[0], 1);
                recs[(size_t)bid * EPB + pos] = make_int4(tt, r | (int)(m << 8), wb, h);
            }
            if (hT) { // d=1 layer-1: srcmask over tail ids
                unsigned m = 0;
#pragma unroll
                for (int b = 0; b < BB; b++) m |= (s_src[BB + b] == h) ? (1u << b) : 0u;
                int pos = atomicAdd(&s_cnt[1], 1);
                recs[(size_t)NE + bid * EPB + pos] = make_int4(tt, r | (int)(m << 8), wb, h);
            }
            if (tT) { // d=0 layer-2: canon = first matching tail slot
                unsigned m = 0;
#pragma unroll
                for (int b = 0; b < BB; b++) m |= (s_src[BB + b] == tt) ? (1u << b) : 0u;
                int canon = __ffs(m) - 1;
                int pos = atomicAdd(&s_cnt[2], 1);
                recs[(size_t)2 * NE + bid * EPB + pos] = make_int4(h, r | (canon << 8), wb, tt);
            }
            if (tH) { // d=1 layer-2: canon = first matching head slot
                unsigned m = 0;
#pragma unroll
                for (int b = 0; b < BB; b++) m |= (s_src[b] == tt) ? (1u << b) : 0u;
                int canon = __ffs(m) - 1;
                int pos = atomicAdd(&s_cnt[3], 1);
                recs[(size_t)3 * NE + bid * EPB + pos] = make_int4(h, r | (canon << 8), wb, tt);
            }
        }
    }
    __syncthreads();
    if (t < 4) counts[bid * 4 + t] = s_cnt[t];

    // Idempotent zero of hidB rows for this stripe's L2-record heads.
    {
        const int wid8 = t >> 6, lane = t & 63;
        float4 z = make_float4(0.f, 0.f, 0.f, 0.f);
        for (int li = 2; li < 4; li++) {
            int c = s_cnt[li];
            float* hb = hidB + (size_t)(li - 2) * N_ENTC * ROW;
            for (int j = wid8; j < c; j += 8) {
                int row = recs[(size_t)li * NE + bid * EPB + j].x;
                float4* p = (float4*)(hb + (size_t)row * ROW);
                p[lane] = z;
                p[lane + 64] = z;
            }
        }
    }

    if (bid == 1) { // zero qacc (both directions) + done counter
        for (int i = t; i < 2 * BB * ROW; i += 512) qaccB[i] = 0.f;
        if (t == 0) *done = 0;
    }
    if (bid == 0) { // relation-attention weights -> global (r0-proven math)
        for (int i = t; i < BB * NDIM; i += 512) {
            int b = i >> 5, k = i & 31;
            s_ht[b * 64 + k] = ent_emb[(size_t)s_src[b] * NDIM + k];
            s_ht[b * 64 + 32 + k] = ent_emb[(size_t)s_src[BB + b] * NDIM + k];
        }
        __syncthreads();
        for (int l = 0; l < 2; l++) {
            for (int i = t; i < BB * 5; i += 512) {
                int b = i / 5, j = i % 5;
                float s = brel[l * 5 + j];
                for (int k = 0; k < 64; k++)
                    s += s_ht[b * 64 + k] * Wrel[l * 320 + k * 5 + j];
                s_h5[i] = fmaxf(s, 0.f);
            }
            __syncthreads();
            for (int i = t; i < BB * ALL_RELC; i += 512) {
                int b = i / ALL_RELC, r = i % ALL_RELC;
                float s = batt[l * ALL_RELC + r];
                for (int j = 0; j < 5; j++)
                    s += s_h5[b * 5 + j] * Watt[l * 5 * ALL_RELC + j * ALL_RELC + r];
                relwG[l * BB * ALL_RELC + i] = 1.0f / (1.0f + expf(-s));
            }
            __syncthreads();
        }
    }
}

__global__ __launch_bounds__(256) void k_msg1(
    const int* __restrict__ head, const int* __restrict__ tail,
    const float* __restrict__ ent_emb, const float* __restrict__ rel_embs,
    const int4* __restrict__ recs, const int* __restrict__ counts,
    const float* __restrict__ relwG, float* __restrict__ hidB)
{
    __shared__ int s_src[32];
    const int t = threadIdx.x, bid = blockIdx.x;
    int4 c4 = ((const int4*)counts)[bid];
    if ((c4.x | c4.y) == 0) return;
    if (t < 32) s_src[t] = (t < BB) ? head[t] : tail[t - BB];
    __syncthreads();
    const int wid = t >> 6, lane = t & 63;
    const float4* rv0 = (const float4*)rel_embs;
    for (int d = 0; d < 2; d++) {
        int c = d ? c4.y : c4.x;
        const int4* R = recs + (size_t)d * NE + (size_t)bid * EPB;
        float* hb = hidB + (size_t)d * N_ENTC * ROW;
        for (int j = wid; j < c; j += 4) {
            int4 rec = R[j];
            int tt = rec.x, r = rec.y & 255;
            unsigned msk = ((unsigned)rec.y) >> 8;
            float w = __int_as_float(rec.z);
            float* drow = hb + (size_t)tt * ROW;
#pragma unroll
            for (int ii = 0; ii < 2; ii++) {
                int i4 = lane + 64 * ii, b = i4 >> 3, kq = i4 & 7;
                if (!((msk >> b) & 1u)) continue;
                float cf = relwG[b * ALL_RELC + r] * w;
                float4 sv = ((const float4*)(ent_emb + (size_t)s_src[d * BB + b] * NDIM))[kq];
                float4 rr = rv0[r * 8 + kq];
                atomicAdd(drow + i4 * 4 + 0, sv.x * cf * rr.x);
                atomicAdd(drow + i4 * 4 + 1, sv.y * cf * rr.y);
                atomicAdd(drow + i4 * 4 + 2, sv.z * cf * rr.z);
                atomicAdd(drow + i4 * 4 + 3, sv.w * cf * rr.w);
            }
        }
    }
}

__global__ __launch_bounds__(512) void k_linmsg2fin(
    const int* __restrict__ head, const int* __restrict__ tail,
    const float* __restrict__ ent_emb, const float* __restrict__ rel_embs,
    const float* __restrict__ Wlin, const float* __restrict__ blin,
    const float* __restrict__ Wr, const float* __restrict__ br,
    const int4* __restrict__ recs, const int* __restrict__ counts,
    const float* __restrict__ relwG, const float* __restrict__ hidB,
    float* __restrict__ qaccB, int* __restrict__ done,
    float* __restrict__ out)
{
    __shared__ float sW[NDIM * NDIM];
    __shared__ float sb[NDIM];
    __shared__ float sx[BB * 128]; // fin: hemb|temb|head_hid|tail_hid
    __shared__ int s_src[32];
    __shared__ int s_canon[2][BB];
    __shared__ int s_last;
    const int t = threadIdx.x, bid = blockIdx.x;
    int4 c4 = ((const int4*)counts)[bid];

    if (t < 32) s_src[t] = (t < BB) ? head[t] : tail[t - BB];
    for (int i = t; i < NDIM * NDIM; i += 512) sW[i] = Wlin[i]; // layer 0
    if (t < NDIM) sb[t] = blin[t];
    __syncthreads();

    // ===== fused lin1 + msg2 (r1 phase-C verbatim; hidC eliminated) =====
    {
        const int wid = t >> 6, lane = t & 63;
        const int b0 = lane >> 3, kq = lane & 7, j0 = kq * 4;
        const float4* rv1 = (const float4*)(rel_embs + (size_t)ALL_RELC * NDIM);
        for (int d = 0; d < 2; d++) {
            int c = d ? c4.w : c4.z;
            const int4* R = recs + (size_t)(2 + d) * NE + (size_t)bid * EPB;
            const float* hb = hidB + (size_t)d * N_ENTC * ROW;
            float* qa = qaccB + (size_t)d * BB * ROW;
            for (int j = wid; j < c; j += 8) {
                int4 rec = R[j];
                int row = rec.x, r = rec.y & 255, canon = (rec.y >> 8) & 15;
                float w = __int_as_float(rec.z);
                float4 rr = rv1[r * 8 + kq];
#pragma unroll
                for (int half = 0; half < 2; half++) {
                    int b = b0 + 8 * half;
                    const float4* src = (const float4*)(hb + (size_t)row * ROW + b * NDIM);
                    float h[NDIM];
#pragma unroll
                    for (int q = 0; q < 8; q++) {
                        float4 v = src[q];
                        h[q * 4 + 0] = v.x; h[q * 4 + 1] = v.y;
                        h[q * 4 + 2] = v.z; h[q * 4 + 3] = v.w;
                    }
                    float a0 = sb[j0], a1 = sb[j0 + 1], a2 = sb[j0 + 2], a3 = sb[j0 + 3];
#pragma unroll
                    for (int k = 0; k < NDIM; k++) {
                        float hk = h[k];
                        float4 wv = *(const float4*)&sW[k * NDIM + j0];
                        a0 += hk * wv.x; a1 += hk * wv.y;
                        a2 += hk * wv.z; a3 += hk * wv.w;
                    }
                    float cf = relwG[BB * ALL_RELC + b * ALL_RELC + r] * w;
                    float* dst = qa + canon * ROW + b * NDIM + j0;
                    atomicAdd(dst + 0, fmaxf(a0, 0.f) * cf * rr.x);
                    atomicAdd(dst + 1, fmaxf(a1, 0.f) * cf * rr.y);
                    atomicAdd(dst + 2, fmaxf(a2, 0.f) * cf * rr.z);
                    atomicAdd(dst + 3, fmaxf(a3, 0.f) * cf * rr.w);
                }
            }
        }
    }

    // ===== last-block fin (done-counter pattern proven r3/r4/r5) =====
    __syncthreads();  // all this block's atomics issued
    __threadfence();  // ... and visible device-wide
    if (t == 0) {
        int old = atomicAdd(done, 1);
        s_last = (old == NSCAN - 1) ? 1 : 0;
    }
    __syncthreads();
    if (!s_last) return;
    __threadfence(); // acquire: all other blocks' qacc atomics

    for (int i = t; i < NDIM * NDIM; i += 512) sW[i] = Wlin[NDIM * NDIM + i]; // layer 1
    if (t < NDIM) sb[t] = blin[NDIM + t];
    if (t < 2 * BB) {
        int dd = t >> 4, b = t & 15;
        int q = s_src[(1 - dd) * BB + b];
        int c = 0;
        for (int bb = 0; bb < BB; bb++)
            if (s_src[(1 - dd) * BB + bb] == q) { c = bb; break; }
        s_canon[dd][b] = c;
    }
    {
        int b = t >> 5, k = t & 31;
        sx[b * 128 + k] = ent_emb[(size_t)s_src[b] * NDIM + k];           // hemb
        sx[b * 128 + 32 + k] = ent_emb[(size_t)s_src[BB + b] * NDIM + k]; // temb
    }
    __syncthreads();
    for (int dd = 0; dd < 2; dd++) { // layer-2 linear on (canon,b) segments
        int b = t >> 5, j = t & 31;
        const float* hrow = qaccB + (size_t)dd * BB * ROW + s_canon[dd][b] * ROW + b * NDIM;
        float s = sb[j];
        for (int k = 0; k < NDIM; k++)
            s += hrow[k] * sW[k * NDIM + j];
        // d=0 (init=head, query=tail) -> tail_hid (col 96); d=1 -> head_hid (col 64)
        sx[b * 128 + (dd == 0 ? 96 : 64) + j] = fmaxf(s, 0.f);
    }
    __syncthreads();
    for (int o = t; o < BB * EVAL_RELC; o += 512) {
        int b = o / EVAL_RELC, r = o % EVAL_RELC;
        float s = br[r];
        for (int k = 0; k < 128; k++)
            s += sx[b * 128 + k] * Wr[k * EVAL_RELC + r];
        out[o] = s;
    }
}

extern "C" void kernel_launch(void* const* d_in, const int* in_sizes, int n_in,
                              void* d_out, int out_size, void* d_ws,
                              size_t ws_size, hipStream_t stream)
{
    const int* head = (const int*)d_in[0];
    const int* tail = (const int*)d_in[1];
    const int* eh = (const int*)d_in[2];
    const int* et = (const int*)d_in[3];
    const int* er = (const int*)d_in[4];
    const float* ew = (const float*)d_in[5];
    const float* ent_emb = (const float*)d_in[6];
    const float* rel_embs = (const float*)d_in[7];
    const float* Wlin = (const float*)d_in[8];
    const float* blin = (const float*)d_in[9];
    const float* Wrel = (const float*)d_in[10];
    const float* brel = (const float*)d_in[11];
    const float* Watt = (const float*)d_in[12];
    const float* batt = (const float*)d_in[13];
    const float* Wr = (const float*)d_in[14];
    const float* br = (const float*)d_in[15];
    float* out = (float*)d_out;
    float* ws = (float*)d_ws;

    // ---- workspace carve (~131 MB; hidC eliminated) ----
    float* hidB = ws;                                      // [2][N][ROW]
    int4* recs = (int4*)(hidB + (size_t)2 * N_ENTC * ROW); // [4][NE] int4
    int* counts = (int*)(recs + (size_t)4 * NE);           // [NSCAN][4]
    float* relwG = (float*)(counts + 4 * NSCAN);           // 7072 floats
    float* qaccB = relwG + 2 * BB * ALL_RELC;              // [2][16][512]
    int* done = (int*)(qaccB + (size_t)2 * BB * ROW);      // 1 int

    k_scan<<<NSCAN, 512, 0, stream>>>(head, tail, eh, et, er, ew, ent_emb,
                                      Wrel, brel, Watt, batt,
                                      recs, counts, relwG, hidB, qaccB, done);
    k_msg1<<<NSCAN, 256, 0, stream>>>(head, tail, ent_emb, rel_embs,
                                      recs, counts, relwG, hidB);
    k_linmsg2fin<<<NSCAN, 512, 0, stream>>>(head, tail, ent_emb, rel_embs,
                                            Wlin, blin, Wr, br, recs, counts,
                                            relwG, hidB, qaccB, done, out);
}